// Round 1
// baseline (298.720 us; speedup 1.0000x reference)
//
#include <hip/hip_runtime.h>

namespace {
constexpr int Bn = 8, Cn = 256, Hn = 64, Wn = 64;
constexpr int Kk = 5, PAD = 2, KMC = 100;   // KMC = UP^2 * K^2
constexpr int CSPLIT = 2;                   // channel-split blocks per (b,h)
constexpr int CPB = Cn / CSPLIT;            // 128 channels per block
constexpr int NWG = Hn * Bn * CSPLIT;       // 1024 workgroups
constexpr int NXCD = 8;
constexpr int CHUNK = NWG / NXCD;           // 128 consecutive origs per XCD
}

// grid 1024 (1-D, XCD-swizzled), block 256 = 4 waves; lane = w (0..63);
// wave wv handles 4 channels per channel-group iteration; each block does
// half the channels (cz). LDS tile is WAVE-PRIVATE -> no block barriers.
__global__ __launch_bounds__(256, 4) void carafe_fwd(
    const float* __restrict__ x,    // [B, C, H, W]
    const float* __restrict__ km,   // [B, 100, H, W]
    float* __restrict__ out)        // [B, C, 2H, 2W]
{
    // XCD-aware chunked swizzle: consecutive `orig` ids land on one XCD.
    // orig = cz + 2*(h + 64*b): h-neighbours (share 4/5 staged x rows) and
    // the cz pair (shares km row) are chunk-local -> that XCD's L2 serves
    // the reuse instead of HBM. One full b-panel per XCD.
    const int wg   = blockIdx.x;
    const int orig = (wg & (NXCD - 1)) * CHUNK + (wg >> 3);
    const int cz   = orig & 1;
    const int h    = (orig >> 1) & (Hn - 1);
    const int b    = orig >> 7;

    const int tid = threadIdx.x;
    const int wv  = tid >> 6;
    const int w   = tid & 63;

    // wave-private staging tile, channel-interleaved for aligned b128 taps
    __shared__ __align__(16) float xs[4][Kk][68][4];

    // zero horizontal halo columns (padded cols 0,1,66,67) once per wave
    if (w < Kk * 4) {
        const int r  = w >> 2;
        const int hc = w & 3;
        const int wp = (hc < 2) ? hc : 64 + hc;
        #pragma unroll
        for (int k = 0; k < 4; ++k) xs[wv][r][wp][k] = 0.0f;
    }

    // per-pixel reassembly weights -> 100 registers (reused over 128 ch)
    float wreg[KMC];
    {
        const float* kmp = km + (((size_t)b * KMC) * Hn + h) * Wn + w;
        #pragma unroll
        for (int ch = 0; ch < KMC; ++ch)
            wreg[ch] = kmp[(size_t)ch * (Hn * Wn)];
    }

    const float* xb = x + (size_t)b * Cn * Hn * Wn;
    float* ob       = out + (size_t)b * Cn * (2 * Hn) * (2 * Wn);

    for (int cb = 0; cb < CPB / 16; ++cb) {
        const int c0 = cz * CPB + cb * 16 + wv * 4;

        // stage 4 channels x 5 rows (rows h-2..h+2, zero-padded) into LDS
        #pragma unroll
        for (int r = 0; r < Kk; ++r) {
            const int hr = h - PAD + r;
            float4 v;
            if (hr >= 0 && hr < Hn) {
                const float* xr = xb + ((size_t)c0 * Hn + hr) * Wn + w;
                v.x = xr[0 * Hn * Wn];
                v.y = xr[1 * Hn * Wn];
                v.z = xr[2 * Hn * Wn];
                v.w = xr[3 * Hn * Wn];
            } else {
                v = make_float4(0.f, 0.f, 0.f, 0.f);
            }
            *(float4*)(&xs[wv][r][w + PAD][0]) = v;
        }

        // Tile is wave-private: no __syncthreads needed. DS ops from one
        // wave complete in order; the waitcnt makes write completion
        // explicit and the "memory" clobber blocks compiler reordering of
        // the cross-lane ds_read before the ds_write.
        asm volatile("s_waitcnt lgkmcnt(0)" ::: "memory");

        float acc[4][4] = {};  // [channel k][subpixel u]
        #pragma unroll
        for (int kh = 0; kh < Kk; ++kh) {
            #pragma unroll
            for (int kw = 0; kw < Kk; ++kw) {
                const float4 tap = *(const float4*)(&xs[wv][kh][w + kw][0]);
                const int t = kh * Kk + kw;
                #pragma unroll
                for (int u = 0; u < 4; ++u) {
                    const float wt = wreg[u * 25 + t];
                    acc[0][u] += tap.x * wt;
                    acc[1][u] += tap.y * wt;
                    acc[2][u] += tap.z * wt;
                    acc[3][u] += tap.w * wt;
                }
            }
        }

        // keep iter i's tap reads ordered before iter i+1's staging writes
        asm volatile("" ::: "memory");

        // out[b, c0+k, 2h+i, 2w+j]; j pair contiguous -> float2 stores,
        // lane-consecutive -> 512B contiguous per wave store
        #pragma unroll
        for (int k = 0; k < 4; ++k) {
            #pragma unroll
            for (int i = 0; i < 2; ++i) {
                float2 o2 = make_float2(acc[k][2 * i + 0], acc[k][2 * i + 1]);
                *(float2*)(&ob[((size_t)(c0 + k) * (2 * Hn) + (2 * h + i)) *
                                   (2 * Wn) + 2 * w]) = o2;
            }
        }
    }
}

extern "C" void kernel_launch(void* const* d_in, const int* in_sizes, int n_in,
                              void* d_out, int out_size, void* d_ws, size_t ws_size,
                              hipStream_t stream)
{
    const float* x  = (const float*)d_in[0];
    const float* km = (const float*)d_in[1];
    float* out      = (float*)d_out;

    dim3 grid(NWG);
    carafe_fwd<<<grid, 256, 0, stream>>>(x, km, out);
}

// Round 2
// 295.922 us; speedup vs baseline: 1.0095x; 1.0095x over previous
//
#include <hip/hip_runtime.h>

namespace {
constexpr int Bn = 8, Cn = 256, Hn = 64, Wn = 64;
constexpr int Kk = 5, PAD = 2, KMC = 100;    // KMC = UP^2 * K^2
constexpr int KK2 = 25;                      // K^2
constexpr int CSPLIT = 2;                    // channel-split blocks per (b,h)
constexpr int CPB = Cn / CSPLIT;             // 128 channels per block
constexpr int NWG = Hn * Bn * CSPLIT;        // 1024 workgroups = 4 blocks/CU
constexpr int NXCD = 8;
constexpr int CHUNK = NWG / NXCD;            // 128 consecutive origs per XCD
}

// grid 1024 (1-D, XCD-swizzled), block 256 = 4 waves; lane = w (0..63);
// wave wv handles 4 channels per channel-group iteration.
// Weights: u=0,1 in shared LDS (block-uniform, per-lane), u=2,3 in 50 regs
// -> ~90 VGPRs total, no spill, LDS 34.6 KB -> 4 blocks/CU co-resident
// (grid == capacity: exactly one residency round, no tail).
__global__ __launch_bounds__(256, 4) void carafe_fwd(
    const float* __restrict__ x,    // [B, C, H, W]
    const float* __restrict__ km,   // [B, 100, H, W]
    float* __restrict__ out)        // [B, C, 2H, 2W]
{
    // XCD-aware chunked swizzle: h-neighbours (share 4/5 staged x rows) and
    // the cz pair (shares km row) are chunk-local -> served by one XCD's L2.
    const int wg   = blockIdx.x;
    const int orig = (wg & (NXCD - 1)) * CHUNK + (wg >> 3);
    const int cz   = orig & 1;
    const int h    = (orig >> 1) & (Hn - 1);
    const int b    = orig >> 7;

    const int tid = threadIdx.x;
    const int wv  = tid >> 6;
    const int w   = tid & 63;

    // wave-private staging tile, channel-interleaved for aligned b128 taps
    __shared__ __align__(16) float xs[4][Kk][68][4];
    // block-shared reassembly weights for u=0,1: [t][w][u]
    __shared__ __align__(8) float kw_lds[KK2][64][2];

    const float* kmb = km + (((size_t)b * KMC) * Hn + h) * Wn;

    // stage km channels 0..49 (u=0,1) into LDS, cooperatively, once
    for (int idx = tid; idx < 2 * KK2 * 64; idx += 256) {
        const int ch = idx >> 6;          // 0..49  (= u*25 + t)
        const int ww = idx & 63;
        const int u  = (ch >= KK2) ? 1 : 0;
        const int t  = ch - u * KK2;
        kw_lds[t][ww][u] = kmb[(size_t)ch * (Hn * Wn) + ww];
    }

    // km channels 50..99 (u=2,3) -> 50 registers (reused over 128 ch)
    float wreg[2 * KK2];
    #pragma unroll
    for (int j = 0; j < 2 * KK2; ++j)
        wreg[j] = kmb[(size_t)(2 * KK2 + j) * (Hn * Wn) + w];

    // zero horizontal halo columns (padded cols 0,1,66,67) once per wave
    if (w < Kk * 4) {
        const int r  = w >> 2;
        const int hc = w & 3;
        const int wp = (hc < 2) ? hc : 64 + hc;
        #pragma unroll
        for (int k = 0; k < 4; ++k) xs[wv][r][wp][k] = 0.0f;
    }

    __syncthreads();  // kw_lds (and halo) visible; only barrier in the kernel

    const float* xb = x + (size_t)b * Cn * Hn * Wn;
    float* ob       = out + (size_t)b * Cn * (2 * Hn) * (2 * Wn);

    for (int cb = 0; cb < CPB / 16; ++cb) {   // 8 channel-group iterations
        const int c0 = cz * CPB + cb * 16 + wv * 4;

        // stage 4 channels x 5 rows (rows h-2..h+2, zero-padded) into LDS
        #pragma unroll
        for (int r = 0; r < Kk; ++r) {
            const int hr = h - PAD + r;
            float4 v;
            if (hr >= 0 && hr < Hn) {
                const float* xr = xb + ((size_t)c0 * Hn + hr) * Wn + w;
                v.x = xr[0 * Hn * Wn];
                v.y = xr[1 * Hn * Wn];
                v.z = xr[2 * Hn * Wn];
                v.w = xr[3 * Hn * Wn];
            } else {
                v = make_float4(0.f, 0.f, 0.f, 0.f);
            }
            *(float4*)(&xs[wv][r][w + PAD][0]) = v;
        }

        // xs tile is wave-private: DS ops from one wave complete in order;
        // waitcnt makes write completion explicit, "memory" clobber stops
        // the compiler moving the cross-lane reads above the writes.
        asm volatile("s_waitcnt lgkmcnt(0)" ::: "memory");

        float acc[4][4] = {};  // [channel k][subpixel u]
        #pragma unroll
        for (int kh = 0; kh < Kk; ++kh) {
            #pragma unroll
            for (int kwi = 0; kwi < Kk; ++kwi) {
                const int t = kh * Kk + kwi;
                const float4 tap = *(const float4*)(&xs[wv][kh][w + kwi][0]);
                const float2 w01 = *(const float2*)(&kw_lds[t][w][0]);
                const float w2 = wreg[t];
                const float w3 = wreg[KK2 + t];
                acc[0][0] += tap.x * w01.x; acc[0][1] += tap.x * w01.y;
                acc[0][2] += tap.x * w2;    acc[0][3] += tap.x * w3;
                acc[1][0] += tap.y * w01.x; acc[1][1] += tap.y * w01.y;
                acc[1][2] += tap.y * w2;    acc[1][3] += tap.y * w3;
                acc[2][0] += tap.z * w01.x; acc[2][1] += tap.z * w01.y;
                acc[2][2] += tap.z * w2;    acc[2][3] += tap.z * w3;
                acc[3][0] += tap.w * w01.x; acc[3][1] += tap.w * w01.y;
                acc[3][2] += tap.w * w2;    acc[3][3] += tap.w * w3;
            }
        }

        // keep iter i's tap reads ordered before iter i+1's staging writes
        asm volatile("" ::: "memory");

        // out[b, c0+k, 2h+i, 2w+j]; j pair contiguous -> float2 stores,
        // lane-consecutive -> 512B contiguous per wave store
        #pragma unroll
        for (int k = 0; k < 4; ++k) {
            #pragma unroll
            for (int i = 0; i < 2; ++i) {
                float2 o2 = make_float2(acc[k][2 * i + 0], acc[k][2 * i + 1]);
                *(float2*)(&ob[((size_t)(c0 + k) * (2 * Hn) + (2 * h + i)) *
                                   (2 * Wn) + 2 * w]) = o2;
            }
        }
    }
}

extern "C" void kernel_launch(void* const* d_in, const int* in_sizes, int n_in,
                              void* d_out, int out_size, void* d_ws, size_t ws_size,
                              hipStream_t stream)
{
    const float* x  = (const float*)d_in[0];
    const float* km = (const float*)d_in[1];
    float* out      = (float*)d_out;

    dim3 grid(NWG);
    carafe_fwd<<<grid, 256, 0, stream>>>(x, km, out);
}

// Round 3
// 211.139 us; speedup vs baseline: 1.4148x; 1.4015x over previous
//
#include <hip/hip_runtime.h>

namespace {
constexpr int Bn = 8, Cn = 256, Hn = 64, Wn = 64;
constexpr int Kk = 5, PAD = 2, KMC = 100;   // KMC = UP^2 * K^2
constexpr int CSPLIT = 2;                   // channel-split blocks per (b,h)
constexpr int CPB = Cn / CSPLIT;            // 128 channels per block
constexpr int NWG = Hn * Bn * CSPLIT;       // 1024 workgroups
constexpr int NXCD = 8;
constexpr int CHUNK = NWG / NXCD;           // 128 consecutive origs per XCD
}

// grid 1024 (1-D, XCD-swizzled), block 256 = 4 waves; lane = w (0..63);
// wave wv handles 4 channels per channel-group iteration; each block does
// half the channels (cz). LDS tile is WAVE-PRIVATE -> no block barriers.
//
// __launch_bounds__ NOTE: second arg MUST stay 2. Declaring 4 makes hipcc
// cap the kernel at 64 VGPRs (8-waves/SIMD class) which spills wreg[100]
// to scratch (+240 MB fetch / +128 MB write, 2x slower — rounds 1-2).
// With (256,2) the body compiles to ~108 VGPR <= 128, so the HARDWARE
// still co-schedules 4 waves/SIMD = 4 blocks/CU; grid 1024 = exactly one
// full residency round.
__global__ __launch_bounds__(256, 2) void carafe_fwd(
    const float* __restrict__ x,    // [B, C, H, W]
    const float* __restrict__ km,   // [B, 100, H, W]
    float* __restrict__ out)        // [B, C, 2H, 2W]
{
    // XCD-aware chunked swizzle: consecutive `orig` ids land on one XCD.
    // orig = cz + 2*(h + 64*b): h-neighbours (share 4/5 staged x rows) and
    // the cz pair (shares km row) are chunk-local -> that XCD's L2 serves
    // the reuse instead of HBM. One full b-panel per XCD.
    const int wg   = blockIdx.x;
    const int orig = (wg & (NXCD - 1)) * CHUNK + (wg >> 3);
    const int cz   = orig & 1;
    const int h    = (orig >> 1) & (Hn - 1);
    const int b    = orig >> 7;

    const int tid = threadIdx.x;
    const int wv  = tid >> 6;
    const int w   = tid & 63;

    // wave-private staging tile, channel-interleaved for aligned b128 taps
    __shared__ __align__(16) float xs[4][Kk][68][4];

    // zero horizontal halo columns (padded cols 0,1,66,67) once per wave
    if (w < Kk * 4) {
        const int r  = w >> 2;
        const int hc = w & 3;
        const int wp = (hc < 2) ? hc : 64 + hc;
        #pragma unroll
        for (int k = 0; k < 4; ++k) xs[wv][r][wp][k] = 0.0f;
    }

    // per-pixel reassembly weights -> 100 registers (reused over 128 ch)
    float wreg[KMC];
    {
        const float* kmp = km + (((size_t)b * KMC) * Hn + h) * Wn + w;
        #pragma unroll
        for (int ch = 0; ch < KMC; ++ch)
            wreg[ch] = kmp[(size_t)ch * (Hn * Wn)];
    }

    const float* xb = x + (size_t)b * Cn * Hn * Wn;
    float* ob       = out + (size_t)b * Cn * (2 * Hn) * (2 * Wn);

    for (int cb = 0; cb < CPB / 16; ++cb) {   // 8 channel-group iterations
        const int c0 = cz * CPB + cb * 16 + wv * 4;

        // stage 4 channels x 5 rows (rows h-2..h+2, zero-padded) into LDS
        #pragma unroll
        for (int r = 0; r < Kk; ++r) {
            const int hr = h - PAD + r;
            float4 v;
            if (hr >= 0 && hr < Hn) {
                const float* xr = xb + ((size_t)c0 * Hn + hr) * Wn + w;
                v.x = xr[0 * Hn * Wn];
                v.y = xr[1 * Hn * Wn];
                v.z = xr[2 * Hn * Wn];
                v.w = xr[3 * Hn * Wn];
            } else {
                v = make_float4(0.f, 0.f, 0.f, 0.f);
            }
            *(float4*)(&xs[wv][r][w + PAD][0]) = v;
        }

        // xs tile is wave-private: DS ops from one wave complete in order;
        // the waitcnt makes write completion explicit and the "memory"
        // clobber blocks compiler reordering of the cross-lane ds_reads
        // above the ds_writes. Verified correct (absmax 0.0, rounds 1-2).
        asm volatile("s_waitcnt lgkmcnt(0)" ::: "memory");

        float acc[4][4] = {};  // [channel k][subpixel u]
        #pragma unroll
        for (int kh = 0; kh < Kk; ++kh) {
            #pragma unroll
            for (int kw = 0; kw < Kk; ++kw) {
                const float4 tap = *(const float4*)(&xs[wv][kh][w + kw][0]);
                const int t = kh * Kk + kw;
                #pragma unroll
                for (int u = 0; u < 4; ++u) {
                    const float wt = wreg[u * 25 + t];
                    acc[0][u] += tap.x * wt;
                    acc[1][u] += tap.y * wt;
                    acc[2][u] += tap.z * wt;
                    acc[3][u] += tap.w * wt;
                }
            }
        }

        // keep iter i's tap reads ordered before iter i+1's staging writes
        asm volatile("" ::: "memory");

        // out[b, c0+k, 2h+i, 2w+j]; j pair contiguous -> float2 stores,
        // lane-consecutive -> 512B contiguous per wave store
        #pragma unroll
        for (int k = 0; k < 4; ++k) {
            #pragma unroll
            for (int i = 0; i < 2; ++i) {
                float2 o2 = make_float2(acc[k][2 * i + 0], acc[k][2 * i + 1]);
                *(float2*)(&ob[((size_t)(c0 + k) * (2 * Hn) + (2 * h + i)) *
                                   (2 * Wn) + 2 * w]) = o2;
            }
        }
    }
}

extern "C" void kernel_launch(void* const* d_in, const int* in_sizes, int n_in,
                              void* d_out, int out_size, void* d_ws, size_t ws_size,
                              hipStream_t stream)
{
    const float* x  = (const float*)d_in[0];
    const float* km = (const float*)d_in[1];
    float* out      = (float*)d_out;

    dim3 grid(NWG);
    carafe_fwd<<<grid, 256, 0, stream>>>(x, km, out);
}

// Round 4
// 198.622 us; speedup vs baseline: 1.5040x; 1.0630x over previous
//
#include <hip/hip_runtime.h>

namespace {
constexpr int Bn = 8, Cn = 256, Hn = 64, Wn = 64;
constexpr int Kk = 5, PAD = 2, KMC = 100;   // KMC = UP^2 * K^2
constexpr int CSPLIT = 2;                   // channel-split blocks per (b,h)
constexpr int CPB = Cn / CSPLIT;            // 128 channels per block
constexpr int NWG = Hn * Bn * CSPLIT;       // 1024 workgroups
constexpr int NXCD = 8;
constexpr int CHUNK = NWG / NXCD;           // 128 consecutive origs per XCD
constexpr int HW = Hn * Wn;                 // 4096
constexpr int NCB = CPB / 16;               // 8 channel-group iterations
}

// grid 1024, block 256 = 4 waves; lane = w; wave handles 4 channels/iter.
// Round-4 structure: ASYNC staging via global_load_lds(width 4) into a
// double-buffered wave-private LDS tile, counted s_waitcnt vmcnt(N)
// (never 0 in steady state) so next-tile loads stay in flight under the
// 400-fmac compute block. No block barriers (tile is wave-private).
//
// __launch_bounds__ MUST stay (256,2): declaring 4 caps arch VGPRs at 64
// -> wreg[100] spills to scratch (rounds 1-2, 2x slower). Occupancy
// empirically follows the launch-bounds class (~19% here), so this round
// hides latency inside each wave instead of adding waves.
__global__ __launch_bounds__(256, 2) void carafe_fwd(
    const float* __restrict__ x,    // [B, C, H, W]
    const float* __restrict__ km,   // [B, 100, H, W]
    float* __restrict__ out)        // [B, C, 2H, 2W]
{
    // XCD-aware chunked swizzle (kept: FETCH 86.8 -> 23.8 MB in round 3)
    const int wg   = blockIdx.x;
    const int orig = (wg & (NXCD - 1)) * CHUNK + (wg >> 3);
    const int cz   = orig & 1;
    const int h    = (orig >> 1) & (Hn - 1);
    const int b    = orig >> 7;

    const int tid = threadIdx.x;
    const int wv  = tid >> 6;
    const int w   = tid & 63;

    // double-buffered wave-private staging: [wave][buf][row][col][ch]
    __shared__ __align__(16) float xs[4][2][Kk][68][4];
    __shared__ float dummy[64];   // discard target for out-of-range rows

    // zero both buffers once: invalid rows + halo cols stay zero forever
    {
        float* slab = &xs[wv][0][0][0][0];
        for (int i = w; i < 2 * Kk * 68 * 4; i += 64) slab[i] = 0.0f;
    }
    // DS zero-writes must land before the async VMEM->LDS writes (different
    // pipes, no mutual order). One-time fence.
    asm volatile("s_waitcnt lgkmcnt(0)" ::: "memory");

    // per-pixel reassembly weights -> 100 registers (reused over 128 ch)
    float wreg[KMC];
    {
        const float* kmp = km + (((size_t)b * KMC) * Hn + h) * Wn + w;
        #pragma unroll
        for (int ch = 0; ch < KMC; ++ch)
            wreg[ch] = kmp[(size_t)ch * HW];
    }

    const float* xb = x + (size_t)b * Cn * HW;
    float* ob       = out + (size_t)b * Cn * (2 * Hn) * (2 * Wn);

    // staging lane split: lane l -> channel (l&3), col (l>>2) of a 16-col
    // chunk. LDS dest = chunk_base + lane*4 because (l>>2)*16B + (l&3)*4B
    // == l*4B in the [col][ch] interleaved layout.
    const int sl_ch = w & 3;
    const int sl_cl = w >> 2;

    // Always issues exactly 20 global_load_lds (uniform vmcnt bookkeeping):
    // out-of-range rows load a clamped address into the dummy slot.
    auto STAGE = [&](int bi, int c0s) {
        #pragma unroll
        for (int r = 0; r < Kk; ++r) {
            const int hr  = h - PAD + r;
            const int hrc = hr < 0 ? 0 : (hr >= Hn ? Hn - 1 : hr);
            const bool valid = (hr == hrc);                 // wave-uniform
            const float* srow =
                xb + (size_t)(c0s + sl_ch) * HW + hrc * Wn + sl_cl;
            #pragma unroll
            for (int q = 0; q < 4; ++q) {
                float* d = valid ? &xs[wv][bi][r][2 + 16 * q][0] : &dummy[0];
                __builtin_amdgcn_global_load_lds(
                    (const __attribute__((address_space(1))) void*)(srow + 16 * q),
                    (__attribute__((address_space(3))) void*)d, 4, 0, 0);
            }
        }
    };

    STAGE(0, cz * CPB + wv * 4);   // prologue: fill buffer 0

    #pragma unroll 1
    for (int cb = 0; cb < NCB; ++cb) {
        const int c0 = cz * CPB + cb * 16 + wv * 4;

        if (cb + 1 < NCB)
            STAGE((cb + 1) & 1, c0 + 16);   // async prefetch next group

        // Wait for THIS buffer's 20 loads; newer in-flight VMEM ops:
        //   cb==0      : STAGE_1 (20)                      -> vmcnt(20)
        //   0<cb<NCB-1 : stores_{cb-1} (8) + STAGE_{cb+1}(20) -> vmcnt(28)
        //   cb==NCB-1  : stores_{cb-1} (8)                 -> vmcnt(8)
        // In-order vmcnt retirement makes these exact; asm memory clobbers
        // pin the STAGE/store ops inside their iteration windows.
        if (cb == 0)            asm volatile("s_waitcnt vmcnt(20)" ::: "memory");
        else if (cb + 1 < NCB)  asm volatile("s_waitcnt vmcnt(28)" ::: "memory");
        else                    asm volatile("s_waitcnt vmcnt(8)"  ::: "memory");

        const int bi = cb & 1;
        float acc[4][4] = {};  // [channel k][subpixel u]
        #pragma unroll
        for (int kh = 0; kh < Kk; ++kh) {
            #pragma unroll
            for (int kw = 0; kw < Kk; ++kw) {
                const float4 tap = *(const float4*)(&xs[wv][bi][kh][w + kw][0]);
                const int t = kh * Kk + kw;
                #pragma unroll
                for (int u = 0; u < 4; ++u) {
                    const float wt = wreg[u * 25 + t];
                    acc[0][u] += tap.x * wt;
                    acc[1][u] += tap.y * wt;
                    acc[2][u] += tap.z * wt;
                    acc[3][u] += tap.w * wt;
                }
            }
        }

        // out[b, c0+k, 2h+i, 2w+j]; 8 global_store_dwordx2 per iteration
        #pragma unroll
        for (int k = 0; k < 4; ++k) {
            #pragma unroll
            for (int i = 0; i < 2; ++i) {
                float2 o2 = make_float2(acc[k][2 * i + 0], acc[k][2 * i + 1]);
                *(float2*)(&ob[((size_t)(c0 + k) * (2 * Hn) + (2 * h + i)) *
                                   (2 * Wn) + 2 * w]) = o2;
            }
        }
    }
}

extern "C" void kernel_launch(void* const* d_in, const int* in_sizes, int n_in,
                              void* d_out, int out_size, void* d_ws, size_t ws_size,
                              hipStream_t stream)
{
    const float* x  = (const float*)d_in[0];
    const float* km = (const float*)d_in[1];
    float* out      = (float*)d_out;

    dim3 grid(NWG);
    carafe_fwd<<<grid, 256, 0, stream>>>(x, km, out);
}

// Round 5
// 198.453 us; speedup vs baseline: 1.5052x; 1.0009x over previous
//
#include <hip/hip_runtime.h>

namespace {
constexpr int Bn = 8, Cn = 256, Hn = 64, Wn = 64;
constexpr int Kk = 5, PAD = 2, KMC = 100;   // KMC = UP^2 * K^2
constexpr int SLICES = 8;                   // channel-slice blocks per (b,h)
constexpr int CPB = Cn / SLICES;            // 32 channels per block
constexpr int NCB = CPB / 4;                // 8 channel-group iterations
constexpr int NWG = Hn * Bn * SLICES;       // 4096 single-wave blocks
constexpr int NXCD = 8;
constexpr int CHUNK = NWG / NXCD;           // 512 -> one batch image per XCD
constexpr int HW = Hn * Wn;                 // 4096
}

// Round 5: SINGLE-WAVE blocks (64 threads), grid 4096. Waves were already
// fully independent (wave-private LDS, no barriers) — 1-wave blocks let the
// HW pack residency by actual resources (VGPR ~112 -> 4 waves/SIMD, LDS
// 11.1 KB -> 14 blocks/CU) instead of the 2-blocks/CU launch-bounds class,
// and decorrelate wave phases so one block's staging latency hides under
// another's FMA stream. Per-wave body identical to round 4 (async
// global_load_lds double-buffer + counted vmcnt, never 0 in steady state).
//
// __launch_bounds__ 2nd arg MUST stay 2: declaring 4 caps VGPRs at 64 ->
// wreg[100] spills to scratch (rounds 1-2, 2x slower). (64,2) keeps the
// verified 256-VGPR budget class.
__global__ __launch_bounds__(64, 2) void carafe_fwd(
    const float* __restrict__ x,    // [B, C, H, W]
    const float* __restrict__ km,   // [B, 100, H, W]
    float* __restrict__ out)        // [B, C, 2H, 2W]
{
    // XCD-chunked swizzle: orig = slice + 8*(h + 64*b), CHUNK=512 ->
    // XCD i serves batch image i: its x-panel (4 MB) == its L2 capacity;
    // the 8 slice-blocks of one (b,h) share the km row in L2; h-neighbours
    // share 4/5 x rows.
    const int wg   = blockIdx.x;
    const int orig = (wg & (NXCD - 1)) * CHUNK + (wg >> 3);
    const int sl   = orig & (SLICES - 1);
    const int h    = (orig >> 3) & (Hn - 1);
    const int b    = orig >> 9;

    const int w = threadIdx.x;   // lane 0..63

    // double-buffered wave-private staging: [buf][row][col][ch]
    __shared__ __align__(16) float xs[2][Kk][68][4];
    __shared__ float dummy[64];   // discard target for out-of-range rows

    // zero both buffers once: invalid rows + halo cols stay zero forever
    {
        float* slab = &xs[0][0][0][0];
        for (int i = w; i < 2 * Kk * 68 * 4; i += 64) slab[i] = 0.0f;
    }
    // DS zero-writes must complete before any async VMEM->LDS write lands
    asm volatile("s_waitcnt lgkmcnt(0)" ::: "memory");

    // per-pixel reassembly weights -> 100 registers (reused over 32 ch)
    float wreg[KMC];
    {
        const float* kmp = km + (((size_t)b * KMC) * Hn + h) * Wn + w;
        #pragma unroll
        for (int ch = 0; ch < KMC; ++ch)
            wreg[ch] = kmp[(size_t)ch * HW];
    }

    const float* xb = x + (size_t)b * Cn * HW;
    float* ob       = out + (size_t)b * Cn * (2 * Hn) * (2 * Wn);

    // staging lane split: lane l -> channel (l&3), col (l>>2) of a 16-col
    // chunk; LDS dest = chunk_base + lane*4 in the [col][ch] layout.
    const int sl_ch = w & 3;
    const int sl_cl = w >> 2;

    // Always exactly 20 global_load_lds (uniform vmcnt bookkeeping):
    // out-of-range rows load a clamped address into the dummy slot.
    auto STAGE = [&](int bi, int c0s) {
        #pragma unroll
        for (int r = 0; r < Kk; ++r) {
            const int hr  = h - PAD + r;
            const int hrc = hr < 0 ? 0 : (hr >= Hn ? Hn - 1 : hr);
            const bool valid = (hr == hrc);                 // wave-uniform
            const float* srow =
                xb + (size_t)(c0s + sl_ch) * HW + hrc * Wn + sl_cl;
            #pragma unroll
            for (int q = 0; q < 4; ++q) {
                float* d = valid ? &xs[bi][r][2 + 16 * q][0] : &dummy[0];
                __builtin_amdgcn_global_load_lds(
                    (const __attribute__((address_space(1))) void*)(srow + 16 * q),
                    (__attribute__((address_space(3))) void*)d, 4, 0, 0);
            }
        }
    };

    const int cbase = sl * CPB;
    STAGE(0, cbase);               // prologue: fill buffer 0

    #pragma unroll 1
    for (int cb = 0; cb < NCB; ++cb) {
        const int c0 = cbase + cb * 4;

        if (cb + 1 < NCB)
            STAGE((cb + 1) & 1, c0 + 4);   // async prefetch next group

        // Wait for THIS buffer's 20 loads; newer in-flight VMEM ops:
        //   cb==0      : STAGE_1 (20)                        -> vmcnt(20)
        //   0<cb<NCB-1 : stores_{cb-1} (8) + STAGE_{cb+1}(20) -> vmcnt(28)
        //   cb==NCB-1  : stores_{cb-1} (8)                   -> vmcnt(8)
        if (cb == 0)            asm volatile("s_waitcnt vmcnt(20)" ::: "memory");
        else if (cb + 1 < NCB)  asm volatile("s_waitcnt vmcnt(28)" ::: "memory");
        else                    asm volatile("s_waitcnt vmcnt(8)"  ::: "memory");

        const int bi = cb & 1;
        float acc[4][4] = {};  // [channel k][subpixel u]
        #pragma unroll
        for (int kh = 0; kh < Kk; ++kh) {
            #pragma unroll
            for (int kw = 0; kw < Kk; ++kw) {
                const float4 tap = *(const float4*)(&xs[bi][kh][w + kw][0]);
                const int t = kh * Kk + kw;
                #pragma unroll
                for (int u = 0; u < 4; ++u) {
                    const float wt = wreg[u * 25 + t];
                    acc[0][u] += tap.x * wt;
                    acc[1][u] += tap.y * wt;
                    acc[2][u] += tap.z * wt;
                    acc[3][u] += tap.w * wt;
                }
            }
        }

        // out[b, c0+k, 2h+i, 2w+j]; 8 global_store_dwordx2 per iteration,
        // lane-consecutive -> 512B contiguous per store
        #pragma unroll
        for (int k = 0; k < 4; ++k) {
            #pragma unroll
            for (int i = 0; i < 2; ++i) {
                float2 o2 = make_float2(acc[k][2 * i + 0], acc[k][2 * i + 1]);
                *(float2*)(&ob[((size_t)(c0 + k) * (2 * Hn) + (2 * h + i)) *
                                   (2 * Wn) + 2 * w]) = o2;
            }
        }
    }
}

extern "C" void kernel_launch(void* const* d_in, const int* in_sizes, int n_in,
                              void* d_out, int out_size, void* d_ws, size_t ws_size,
                              hipStream_t stream)
{
    const float* x  = (const float*)d_in[0];
    const float* km = (const float*)d_in[1];
    float* out      = (float*)d_out;

    dim3 grid(NWG);
    carafe_fwd<<<grid, 64, 0, stream>>>(x, km, out);
}